// Round 1
// 1211.299 us; speedup vs baseline: 1.6276x; 1.6276x over previous
//
#include <hip/hip_runtime.h>
#include <stdint.h>

// Problem constants
#define VOCAB 50000
#define EMBD  128
#define HID   256
#define G4    1024   // 4*HID
#define BATCH 256
#define TSEQ  512
#define OUTD  64

typedef __attribute__((ext_vector_type(4))) float f32x4;
typedef __attribute__((ext_vector_type(8))) short short8;
typedef __attribute__((ext_vector_type(4))) unsigned short ushort4_t;

__device__ inline unsigned short f2bf(float f) {
  unsigned u = __float_as_uint(f);
  u += 0x7fffu + ((u >> 16) & 1u);     // round-nearest-even
  return (unsigned short)(u >> 16);
}
__device__ inline float bf2f(unsigned short u) {
  return __uint_as_float(((unsigned)u) << 16);
}
__device__ inline short8 pack2(f32x4 a, f32x4 b) {
  short8 r;
  r[0] = (short)f2bf(a[0]); r[1] = (short)f2bf(a[1]);
  r[2] = (short)f2bf(a[2]); r[3] = (short)f2bf(a[3]);
  r[4] = (short)f2bf(b[0]); r[5] = (short)f2bf(b[1]);
  r[6] = (short)f2bf(b[2]); r[7] = (short)f2bf(b[3]);
  return r;
}

// LDS-only barrier (R6 win): h double-buffer needs only LDS ordering; global
// prefetch loads stay in flight across it.
__device__ inline void barrier_lds_only() {
  asm volatile("s_waitcnt lgkmcnt(0)\n\ts_barrier" ::: "memory");
}

// Wx layout: Wx[v][u*4 + nt], u = h-unit 0..255, nt in {i,f,g,o}; oj = nt*256+u.

// ---------------------------------------------------------------------------
// K1: Wx[v][u*4+nt] = bf16( b_ih[oj] + b_hh[oj] + emb[v] . W_ih[oj] )
// (unchanged from previous round)
// ---------------------------------------------------------------------------
__global__ __launch_bounds__(256) void wx_k1(
    const float* __restrict__ emb, const float* __restrict__ Wih,
    const float* __restrict__ bih, const float* __restrict__ bhh,
    unsigned short* __restrict__ Wx) {
  const int w1 = threadIdx.x >> 6, lane = threadIdx.x & 63;
  const int quad = lane >> 4, n = lane & 15;
  const int combo = blockIdx.y * 4 + w1;        // 0..15 -> units combo*16..+15

  float bias[4];
  short8 bfr[4][4];
#pragma unroll
  for (int nt = 0; nt < 4; ++nt) {
    const int oj = nt * 256 + combo * 16 + n;
    bias[nt] = bih[oj] + bhh[oj];
#pragma unroll
    for (int kc = 0; kc < 4; ++kc) {
      const f32x4* wp = (const f32x4*)(Wih + (size_t)oj * EMBD + kc * 32 + quad * 8);
      bfr[nt][kc] = pack2(wp[0], wp[1]);
    }
  }

  for (int vt = 0; vt < 4; ++vt) {
    const int vb = blockIdx.x * 64 + vt * 16;
    if (vb >= VOCAB) break;                     // tiles align: 49,984+16 = 50,000
    short8 af[4];
#pragma unroll
    for (int kc = 0; kc < 4; ++kc) {
      const f32x4* ep = (const f32x4*)(emb + (size_t)(vb + n) * EMBD + kc * 32 + quad * 8);
      af[kc] = pack2(ep[0], ep[1]);
    }
    f32x4 acc[4];
#pragma unroll
    for (int nt = 0; nt < 4; ++nt) acc[nt] = (f32x4){0.f, 0.f, 0.f, 0.f};
#pragma unroll
    for (int kc = 0; kc < 4; ++kc)
#pragma unroll
      for (int nt = 0; nt < 4; ++nt)
        acc[nt] = __builtin_amdgcn_mfma_f32_16x16x32_bf16(af[kc], bfr[nt][kc], acc[nt], 0, 0, 0);
#pragma unroll
    for (int rr = 0; rr < 4; ++rr) {
      ushort4_t o;
#pragma unroll
      for (int nt = 0; nt < 4; ++nt) o[nt] = f2bf(acc[nt][rr] + bias[nt]);
      *(ushort4_t*)&Wx[(size_t)(vb + quad * 4 + rr) * G4 + (combo * 16 + n) * 4] = o;
    }
  }
}

// ---------------------------------------------------------------------------
// K2: LSTM recurrence, R11 restructure.
// 64 WGs x 512 threads; WG = 4 batch rows (slots quad*4 of the MFMA C tile),
// ALL 256 h-units, one lgkm-only barrier/step.
//   - 4 rows/WG: pointwise shrinks to 2gl x 1rr per wave (1/4 the exp/rcp
//     issue of the 16-row version); MFMA count unchanged (M underfilled,
//     free); 64 CUs active instead of 16.
//   - merged-gl K loop: each h A-frag ds_read feeds 8 MFMAs (both gl x 4 nt)
//     -> A reads 16->8 b128/wave/step, 8 independent MFMA chains (ILP x2).
//     Funded by the registers freed by 4 rows (wxbuf/cst/idx/toko shrink)
//     and by dropping lastreg (predicated direct global store at t==idx).
//   - token offsets prescaled + staged in LDS during the zpos scan: the
//     per-step token fetch is an lgkm broadcast read, so no per-step
//     vmcnt(0) drain of the Wx prefetch queue.
// W_hh: K-chunks 0..5 in regs (192/lane), 6..7 in LDS (unchanged).
// ---------------------------------------------------------------------------
__global__ __launch_bounds__(512, 2) void lstm_k2(
    const int* __restrict__ x, const float* __restrict__ Whh,
    const unsigned short* __restrict__ Wx,
    float* __restrict__ lastH) {               // [256][256]
  const int group = blockIdx.x;                // 64 groups of 4 batch rows
  const int rowbase = group * 4;
  const int tid = threadIdx.x;
  const int w = tid >> 6, lane = tid & 63;
  const int quad = lane >> 4, n = lane & 15;

  __shared__ __attribute__((aligned(16))) unsigned short h_lds[2][16][264];   // 16.5 KB
  __shared__ __attribute__((aligned(16))) unsigned short wlds[8][2][4][2][64][8]; // 128 KB
  __shared__ int xoff[4][TSEQ];                // 8 KB, prescaled token offsets
  __shared__ int zpos[4];

  if (tid < 4) zpos[tid] = 1 << 30;
  __syncthreads();
  // scan tokens: pad position + stage prescaled Wx row offsets in LDS
  for (int i = tid; i < 4 * TSEQ; i += 512) {
    const int row = i >> 9, tc = i & 511;
    const int tok = x[(size_t)(rowbase + row) * TSEQ + tc];
    if (tok == 0) atomicMin(&zpos[row], tc);
    xoff[row][tc] = tok * G4;
  }
  // zero BOTH h buffers: only rows {0,4,8,12} are ever written; the other
  // 12 slots must stay zero forever (they are the unused M rows of the MFMA)
  for (int i = tid; i < 2 * 16 * 264; i += 512) ((unsigned short*)h_lds)[i] = 0;

  // LDS weights: K-chunks 6,7 (B-frag layout)
#pragma unroll
  for (int gl = 0; gl < 2; ++gl)
#pragma unroll
    for (int nt = 0; nt < 4; ++nt)
#pragma unroll
      for (int kcl = 0; kcl < 2; ++kcl) {
        const int oj = nt * 256 + (2 * w + gl) * 16 + n;
        const f32x4* wp = (const f32x4*)(Whh + (size_t)oj * HID + (6 + kcl) * 32 + quad * 8);
        *(short8*)&wlds[w][gl][nt][kcl][lane][0] = pack2(wp[0], wp[1]);
      }

  // register weights: K-chunks 0..5.  B[k][col=n] = Whh[oj(n)][k].
  short8 bfr[2][4][6];
#pragma unroll
  for (int gl = 0; gl < 2; ++gl)
#pragma unroll
    for (int nt = 0; nt < 4; ++nt) {
      const int oj = nt * 256 + (2 * w + gl) * 16 + n;
      const float* wrow = Whh + (size_t)oj * HID;
#pragma unroll
      for (int kc = 0; kc < 6; ++kc) {
        const f32x4* wp = (const f32x4*)(wrow + kc * 32 + quad * 8);
        bfr[gl][nt][kc] = pack2(wp[0], wp[1]);
      }
    }

  float cst[2];
#pragma unroll
  for (int gl = 0; gl < 2; ++gl) cst[gl] = 0.f;

  __syncthreads();   // zpos, xoff, h(0), wlds ready
  const int idxq = zpos[quad] - 1;             // last valid t for this lane's row

  // initial Wx load (t=0) + token offset for t=1 (from LDS)
  ushort4_t wxbuf[2];
  {
    const int o0 = xoff[quad][0];
#pragma unroll
    for (int gl = 0; gl < 2; ++gl)
      wxbuf[gl] = *(const ushort4_t*)(Wx + (size_t)(unsigned)o0 + ((2 * w + gl) * 16 + n) * 4);
  }
  int toko = xoff[quad][1];

  // fused LSTM pointwise: 5 exp + 3 rcp (validated in R8):
  //   c' = c*rcp(1+e^-f) + (e^{2g}-1)*rcp((1+e^-i)(e^{2g}+1))
  //   h  = (e^{2c'}-1)*rcp((1+e^-o)(e^{2c'}+1))
  for (int t = 0; t < TSEQ; ++t) {
    const int p = t & 1, pn = p ^ 1;
    const int tnn = (t + 2 < TSEQ) ? (t + 2) : (TSEQ - 1);

    // acc init from prefetched Wx (has both biases); only C-row quad*4 (rr=0)
    // carries a real batch row -- components 1..3 are the zero M-rows.
    f32x4 acc[2][4];
#pragma unroll
    for (int gl = 0; gl < 2; ++gl)
#pragma unroll
      for (int nt = 0; nt < 4; ++nt) {
        f32x4 a0 = (f32x4){0.f, 0.f, 0.f, 0.f};
        a0[0] = bf2f(wxbuf[gl][nt]);
        acc[gl][nt] = a0;
      }
    // re-issue Wx prefetch for t+1 (consumed only next step -> full-step
    // latency overlap; nothing in this loop drains vmcnt)
#pragma unroll
    for (int gl = 0; gl < 2; ++gl)
      wxbuf[gl] = *(const ushort4_t*)(Wx + (size_t)(unsigned)toko + ((2 * w + gl) * 16 + n) * 4);
    // token offset for t+2: LDS broadcast read (lgkm, drained by the barrier)
    const int tok_next = xoff[quad][tnn];

    // merged GEMM: each h A-frag read ONCE, feeds 8 MFMAs (2gl x 4nt).
    // K-chunks 0..5 from register B-frags
#pragma unroll
    for (int kc = 0; kc < 6; ++kc) {
      const short8 a = *(const short8*)&h_lds[p][n][kc * 32 + quad * 8];
#pragma unroll
      for (int gl = 0; gl < 2; ++gl)
#pragma unroll
        for (int nt = 0; nt < 4; ++nt)
          acc[gl][nt] = __builtin_amdgcn_mfma_f32_16x16x32_bf16(a, bfr[gl][nt][kc], acc[gl][nt], 0, 0, 0);
    }
    // K-chunks 6..7 from LDS B-frags
#pragma unroll
    for (int kcl = 0; kcl < 2; ++kcl) {
      const short8 a = *(const short8*)&h_lds[p][n][(6 + kcl) * 32 + quad * 8];
#pragma unroll
      for (int gl = 0; gl < 2; ++gl)
#pragma unroll
        for (int nt = 0; nt < 4; ++nt) {
          const short8 b = *(const short8*)&wlds[w][gl][nt][kcl][lane][0];
          acc[gl][nt] = __builtin_amdgcn_mfma_f32_16x16x32_bf16(a, b, acc[gl][nt], 0, 0, 0);
        }
    }

    toko = tok_next;

    // fused pointwise, rr=0 only: lane owns (row rowbase+quad, unit u)
#pragma unroll
    for (int gl = 0; gl < 2; ++gl) {
      const int u = (2 * w + gl) * 16 + n;
      const float ei = __expf(-acc[gl][0][0]), ef = __expf(-acc[gl][1][0]);
      const float eg2 = __expf(2.0f * acc[gl][2][0]), eo = __expf(-acc[gl][3][0]);
      const float r1 = __builtin_amdgcn_rcpf(1.0f + ef);
      const float r2 = __builtin_amdgcn_rcpf((1.0f + ei) * (eg2 + 1.0f));
      const float ci = cst[gl] * r1 + (eg2 - 1.0f) * r2;
      cst[gl] = ci;
      const float ec2 = __expf(2.0f * ci);
      const float r3 = __builtin_amdgcn_rcpf((1.0f + eo) * (ec2 + 1.0f));
      const float hv = (ec2 - 1.0f) * r3;
      h_lds[pn][quad * 4][u] = f2bf(hv);
      // gathered last-valid h: fires exactly once per row over the 512 steps
      // (exec-masked store; s_cbranch_execz skips it the other 511 times)
      if (t == idxq) lastH[(size_t)(rowbase + quad) * HID + u] = hv;
    }

    barrier_lds_only();  // h(t+1) complete; global prefetches stay in flight
  }
}

// ---------------------------------------------------------------------------
// K3: logits + softmax. One wave per batch row; lane j = output j.
// ---------------------------------------------------------------------------
__global__ __launch_bounds__(64) void head_k3(
    const float* __restrict__ lastH, const float* __restrict__ Wout,
    const float* __restrict__ bout, float* __restrict__ out) {
  const int b = blockIdx.x, j = threadIdx.x;
  const f32x4* hv = (const f32x4*)(lastH + (size_t)b * HID);
  const f32x4* wv = (const f32x4*)(Wout + (size_t)j * HID);
  float acc = bout[j];
#pragma unroll 8
  for (int k = 0; k < HID / 4; ++k) {
    const f32x4 a = hv[k], ww = wv[k];
    acc += a[0] * ww[0] + a[1] * ww[1] + a[2] * ww[2] + a[3] * ww[3];
  }
  float m = acc;
  for (int s = 32; s > 0; s >>= 1) m = fmaxf(m, __shfl_xor(m, s, 64));
  const float e = __expf(acc - m);
  float ssum = e;
  for (int s = 32; s > 0; s >>= 1) ssum += __shfl_xor(ssum, s, 64);
  out[(size_t)b * OUTD + j] = e / ssum;
}

// ---------------------------------------------------------------------------
extern "C" void kernel_launch(void* const* d_in, const int* in_sizes, int n_in,
                              void* d_out, int out_size, void* d_ws, size_t ws_size,
                              hipStream_t stream) {
  const int*   x    = (const int*)d_in[0];
  const float* emb  = (const float*)d_in[1];
  const float* Wih  = (const float*)d_in[2];
  const float* Whh  = (const float*)d_in[3];
  const float* bih  = (const float*)d_in[4];
  const float* bhh  = (const float*)d_in[5];
  const float* Wout = (const float*)d_in[6];
  const float* bout = (const float*)d_in[7];
  float* out = (float*)d_out;

  // workspace carve (~97.9 MiB)
  char* ws = (char*)d_ws;
  unsigned short* Wx = (unsigned short*)ws;                 // 102,400,000 B
  float* lastH = (float*)(ws + 102400000);                  // 262,144 B

  hipLaunchKernelGGL(wx_k1, dim3(782, 4), dim3(256), 0, stream,
                     emb, Wih, bih, bhh, Wx);
  hipLaunchKernelGGL(lstm_k2, dim3(64), dim3(512), 0, stream,
                     x, Whh, Wx, lastH);
  hipLaunchKernelGGL(head_k3, dim3(BATCH), dim3(OUTD), 0, stream,
                     lastH, Wout, bout, out);
}

// Round 3
// 1054.813 us; speedup vs baseline: 1.8691x; 1.1484x over previous
//
#include <hip/hip_runtime.h>
#include <stdint.h>

// Problem constants
#define VOCAB 50000
#define EMBD  128
#define HID   256
#define G4    1024   // 4*HID
#define BATCH 256
#define TSEQ  512
#define OUTD  64

typedef __attribute__((ext_vector_type(4))) float f32x4;
typedef __attribute__((ext_vector_type(8))) short short8;
typedef __attribute__((ext_vector_type(4))) unsigned short ushort4_t;
typedef __attribute__((ext_vector_type(8))) unsigned short ushort8_t;

__device__ inline unsigned short f2bf(float f) {
  unsigned u = __float_as_uint(f);
  u += 0x7fffu + ((u >> 16) & 1u);     // round-nearest-even
  return (unsigned short)(u >> 16);
}
__device__ inline float bf2f(unsigned short u) {
  return __uint_as_float(((unsigned)u) << 16);
}
__device__ inline short8 pack2(f32x4 a, f32x4 b) {
  short8 r;
  r[0] = (short)f2bf(a[0]); r[1] = (short)f2bf(a[1]);
  r[2] = (short)f2bf(a[2]); r[3] = (short)f2bf(a[3]);
  r[4] = (short)f2bf(b[0]); r[5] = (short)f2bf(b[1]);
  r[6] = (short)f2bf(b[2]); r[7] = (short)f2bf(b[3]);
  return r;
}

// LDS-only barrier (R6 win): h double-buffer needs only LDS ordering; global
// prefetch loads stay in flight across it.
__device__ inline void barrier_lds_only() {
  asm volatile("s_waitcnt lgkmcnt(0)\n\ts_barrier" ::: "memory");
}

// Wx layout: Wx[v][u*4 + nt], u = h-unit, nt in {i,f,g,o}; oj = nt*256 + u.
// K2 unit mapping u = w*32 + 2n + gl (R13: adjacent gl outputs -> one packed
// b32 h-write, one coalesced 16B Wx prefetch per lane).

// ---------------------------------------------------------------------------
// K1: Wx[v][u*4+nt] = bf16( b_ih[oj] + b_hh[oj] + emb[v] . W_ih[oj] )
// (R11 version, unscaled — reverted from R12's gate pre-scaling)
// ---------------------------------------------------------------------------
__global__ __launch_bounds__(256) void wx_k1(
    const float* __restrict__ emb, const float* __restrict__ Wih,
    const float* __restrict__ bih, const float* __restrict__ bhh,
    unsigned short* __restrict__ Wx) {
  const int w1 = threadIdx.x >> 6, lane = threadIdx.x & 63;
  const int quad = lane >> 4, n = lane & 15;
  const int combo = blockIdx.y * 4 + w1;        // 0..15 -> units combo*16..+15

  float bias[4];
  short8 bfr[4][4];
#pragma unroll
  for (int nt = 0; nt < 4; ++nt) {
    const int oj = nt * 256 + combo * 16 + n;
    bias[nt] = bih[oj] + bhh[oj];
#pragma unroll
    for (int kc = 0; kc < 4; ++kc) {
      const f32x4* wp = (const f32x4*)(Wih + (size_t)oj * EMBD + kc * 32 + quad * 8);
      bfr[nt][kc] = pack2(wp[0], wp[1]);
    }
  }

  for (int vt = 0; vt < 4; ++vt) {
    const int vb = blockIdx.x * 64 + vt * 16;
    if (vb >= VOCAB) break;                     // tiles align: 49,984+16 = 50,000
    short8 af[4];
#pragma unroll
    for (int kc = 0; kc < 4; ++kc) {
      const f32x4* ep = (const f32x4*)(emb + (size_t)(vb + n) * EMBD + kc * 32 + quad * 8);
      af[kc] = pack2(ep[0], ep[1]);
    }
    f32x4 acc[4];
#pragma unroll
    for (int nt = 0; nt < 4; ++nt) acc[nt] = (f32x4){0.f, 0.f, 0.f, 0.f};
#pragma unroll
    for (int kc = 0; kc < 4; ++kc)
#pragma unroll
      for (int nt = 0; nt < 4; ++nt)
        acc[nt] = __builtin_amdgcn_mfma_f32_16x16x32_bf16(af[kc], bfr[nt][kc], acc[nt], 0, 0, 0);
#pragma unroll
    for (int rr = 0; rr < 4; ++rr) {
      ushort4_t o;
#pragma unroll
      for (int nt = 0; nt < 4; ++nt) o[nt] = f2bf(acc[nt][rr] + bias[nt]);
      *(ushort4_t*)&Wx[(size_t)(vb + quad * 4 + rr) * G4 + (combo * 16 + n) * 4] = o;
    }
  }
}

// ---------------------------------------------------------------------------
// K2: LSTM recurrence. R13 = R11 numerics (loop-local acc, __expf pointwise)
// + R12 addressing wins:
//  - broadcast-A: only lanes with (n&3)==0 supply real A rows; the other 48
//    lanes read row 1 (always-zero) -> LDS broadcast, ~4x less A-read bank
//    traffic. Value-identical to R11 (phantom rows were zero there too).
//  - unit remap u = w*32+2n+gl: h-write = one packed b32; Wx prefetch = one
//    coalesced 16B load per lane.
//  - XOR-toggled h base offset (hoff ^= 8448): LDS addrs = base+immediate.
// REVERTED from R12 (NaN root cause): inline-asm v_exp_f32 (trans-op hazard
// is invisible to the compiler inside opaque asm -> stale-register reads).
// Back to __expf + unscaled weights, hazard handling compiler-managed.
// ---------------------------------------------------------------------------
__global__ __launch_bounds__(512, 2) void lstm_k2(
    const int* __restrict__ x, const float* __restrict__ Whh,
    const unsigned short* __restrict__ Wx,
    float* __restrict__ lastH) {               // [256][256]
  const int group = blockIdx.x;                // 64 groups of 4 batch rows
  const int rowbase = group * 4;
  const int tid = threadIdx.x;
  const int w = tid >> 6, lane = tid & 63;
  const int quad = lane >> 4, n = lane & 15;

  __shared__ __attribute__((aligned(16))) unsigned short h_lds[2][16][264];   // 16.5 KB
  __shared__ __attribute__((aligned(16))) unsigned short wlds[8][2][4][2][64][8]; // 128 KB
  __shared__ int xoff[4][TSEQ];                // 8 KB, prescaled token offsets
  __shared__ int zpos[4];

  if (tid < 4) zpos[tid] = 1 << 30;
  __syncthreads();
  // scan tokens: pad position + stage prescaled Wx row offsets in LDS
  for (int i = tid; i < 4 * TSEQ; i += 512) {
    const int row = i >> 9, tc = i & 511;
    const int tok = x[(size_t)(rowbase + row) * TSEQ + tc];
    if (tok == 0) atomicMin(&zpos[row], tc);
    xoff[row][tc] = tok * G4;
  }
  // zero BOTH h buffers (real rows 0,4,8,12 need h(0)=0; row 1 is the
  // broadcast-zero row for phantom A lanes and must stay zero forever)
  for (int i = tid; i < 2 * 16 * 264; i += 512) ((unsigned short*)h_lds)[i] = 0;

  // LDS weights: K-chunks 6,7 (B-frag layout)
#pragma unroll
  for (int gl = 0; gl < 2; ++gl)
#pragma unroll
    for (int nt = 0; nt < 4; ++nt)
#pragma unroll
      for (int kcl = 0; kcl < 2; ++kcl) {
        const int oj = nt * 256 + w * 32 + 2 * n + gl;
        const f32x4* wp = (const f32x4*)(Whh + (size_t)oj * HID + (6 + kcl) * 32 + quad * 8);
        *(short8*)&wlds[w][gl][nt][kcl][lane][0] = pack2(wp[0], wp[1]);
      }

  // register weights: K-chunks 0..5.  B[k][col=n] = Whh[oj(n)][k].
  short8 bfr[2][4][6];
#pragma unroll
  for (int gl = 0; gl < 2; ++gl)
#pragma unroll
    for (int nt = 0; nt < 4; ++nt) {
      const int oj = nt * 256 + w * 32 + 2 * n + gl;
      const float* wrow = Whh + (size_t)oj * HID;
#pragma unroll
      for (int kc = 0; kc < 6; ++kc) {
        const f32x4* wp = (const f32x4*)(wrow + kc * 32 + quad * 8);
        bfr[gl][nt][kc] = pack2(wp[0], wp[1]);
      }
    }

  float cst[2];
  cst[0] = 0.f; cst[1] = 0.f;

  __syncthreads();   // zpos, xoff, h(0), wlds ready
  const int idxq = zpos[quad] - 1;             // last valid t for this lane's row

  // per-lane constant byte offsets into h_lds
  // A-read: real lanes (n%4==0) -> row n, k-slice quad; others -> row 1 (zero,
  // broadcast). h-write: row quad*4, units u0=w*32+2n, u0+1 packed as b32.
  const int ard = ((n & 3) == 0) ? (n * 528 + quad * 16) : 528;
  const int awr = quad * 2112 + (w * 32 + 2 * n) * 2;
  const unsigned lanewx = (unsigned)((w * 32 + 2 * n) * 4);
  char* hb = (char*)&h_lds[0][0][0];
  unsigned hoff = 0;                           // read-buffer byte offset; write = hoff^8448

  // initial Wx load (t=0, both gl in one 16B load) + offset for t=1
  ushort8_t wx8 = *(const ushort8_t*)(Wx + (size_t)(unsigned)xoff[quad][0] + lanewx);
  int toko = xoff[quad][1];

  // fused pointwise (R8-validated, 5 exp + 3 rcp):
  //   c' = c*rcp(1+e^-f) + (e^{2g}-1)*rcp((1+e^-i)(e^{2g}+1))
  //   h  = (e^{2c'}-1)*rcp((1+e^-o)(e^{2c'}+1))
  for (int t = 0; t < TSEQ; ++t) {
    const int tnn = (t + 2 < TSEQ) ? (t + 2) : (TSEQ - 1);

    // acc init from prefetched Wx (has both biases); loop-local, full init
    // (R11 semantics): only element 0 (C row quad*4) carries a real batch row.
    f32x4 acc[2][4];
#pragma unroll
    for (int gl = 0; gl < 2; ++gl)
#pragma unroll
      for (int nt = 0; nt < 4; ++nt)
        acc[gl][nt] = (f32x4){bf2f(wx8[gl * 4 + nt]), 0.f, 0.f, 0.f};

    // re-issue Wx prefetch for t+1 (consumed next step -> full-step overlap)
    wx8 = *(const ushort8_t*)(Wx + (size_t)(unsigned)toko + lanewx);
    // token offset for t+2: LDS broadcast read (lgkm, drained by the barrier)
    const int tok_next = xoff[quad][tnn];

    // merged GEMM: each A-frag read once, feeds 8 MFMAs (2gl x 4nt).
    // K-chunks 0..5 from register B-frags
#pragma unroll
    for (int kc = 0; kc < 6; ++kc) {
      const short8 a = *(const short8*)(hb + hoff + ard + kc * 64);
#pragma unroll
      for (int gl = 0; gl < 2; ++gl)
#pragma unroll
        for (int nt = 0; nt < 4; ++nt)
          acc[gl][nt] = __builtin_amdgcn_mfma_f32_16x16x32_bf16(a, bfr[gl][nt][kc], acc[gl][nt], 0, 0, 0);
    }
    // K-chunks 6..7 from LDS B-frags
#pragma unroll
    for (int kcl = 0; kcl < 2; ++kcl) {
      const short8 a = *(const short8*)(hb + hoff + ard + (6 + kcl) * 64);
#pragma unroll
      for (int gl = 0; gl < 2; ++gl)
#pragma unroll
        for (int nt = 0; nt < 4; ++nt) {
          const short8 b = *(const short8*)&wlds[w][gl][nt][kcl][lane][0];
          acc[gl][nt] = __builtin_amdgcn_mfma_f32_16x16x32_bf16(a, b, acc[gl][nt], 0, 0, 0);
        }
    }

    toko = tok_next;

    // fused pointwise, both gl, then one packed h-write
    float hv2[2];
#pragma unroll
    for (int gl = 0; gl < 2; ++gl) {
      const float ei = __expf(-acc[gl][0][0]), ef = __expf(-acc[gl][1][0]);
      const float eg2 = __expf(2.0f * acc[gl][2][0]), eo = __expf(-acc[gl][3][0]);
      const float r1 = __builtin_amdgcn_rcpf(1.0f + ef);
      const float r2 = __builtin_amdgcn_rcpf((1.0f + ei) * (eg2 + 1.0f));
      const float ci = cst[gl] * r1 + (eg2 - 1.0f) * r2;
      cst[gl] = ci;
      const float ec2 = __expf(2.0f * ci);
      const float r3 = __builtin_amdgcn_rcpf((1.0f + eo) * (ec2 + 1.0f));
      hv2[gl] = (ec2 - 1.0f) * r3;
    }
    const unsigned pk = (unsigned)f2bf(hv2[0]) | ((unsigned)f2bf(hv2[1]) << 16);
    *(unsigned*)(hb + (hoff ^ 8448u) + awr) = pk;

    // gathered last-valid h: fires once per row over the 512 steps
    if (t == idxq) {
      const size_t o0 = (size_t)(rowbase + quad) * HID + (w * 32 + 2 * n);
      lastH[o0] = hv2[0];
      lastH[o0 + 1] = hv2[1];
    }

    hoff ^= 8448u;
    barrier_lds_only();  // h(t+1) complete; global prefetches stay in flight
  }
}

// ---------------------------------------------------------------------------
// K3: logits + softmax. One wave per batch row; lane j = output j.
// ---------------------------------------------------------------------------
__global__ __launch_bounds__(64) void head_k3(
    const float* __restrict__ lastH, const float* __restrict__ Wout,
    const float* __restrict__ bout, float* __restrict__ out) {
  const int b = blockIdx.x, j = threadIdx.x;
  const f32x4* hv = (const f32x4*)(lastH + (size_t)b * HID);
  const f32x4* wv = (const f32x4*)(Wout + (size_t)j * HID);
  float acc = bout[j];
#pragma unroll 8
  for (int k = 0; k < HID / 4; ++k) {
    const f32x4 a = hv[k], ww = wv[k];
    acc += a[0] * ww[0] + a[1] * ww[1] + a[2] * ww[2] + a[3] * ww[3];
  }
  float m = acc;
  for (int s = 32; s > 0; s >>= 1) m = fmaxf(m, __shfl_xor(m, s, 64));
  const float e = __expf(acc - m);
  float ssum = e;
  for (int s = 32; s > 0; s >>= 1) ssum += __shfl_xor(ssum, s, 64);
  out[(size_t)b * OUTD + j] = e / ssum;
}

// ---------------------------------------------------------------------------
extern "C" void kernel_launch(void* const* d_in, const int* in_sizes, int n_in,
                              void* d_out, int out_size, void* d_ws, size_t ws_size,
                              hipStream_t stream) {
  const int*   x    = (const int*)d_in[0];
  const float* emb  = (const float*)d_in[1];
  const float* Wih  = (const float*)d_in[2];
  const float* Whh  = (const float*)d_in[3];
  const float* bih  = (const float*)d_in[4];
  const float* bhh  = (const float*)d_in[5];
  const float* Wout = (const float*)d_in[6];
  const float* bout = (const float*)d_in[7];
  float* out = (float*)d_out;

  // workspace carve (~97.9 MiB)
  char* ws = (char*)d_ws;
  unsigned short* Wx = (unsigned short*)ws;                 // 102,400,000 B
  float* lastH = (float*)(ws + 102400000);                  // 262,144 B

  hipLaunchKernelGGL(wx_k1, dim3(782, 4), dim3(256), 0, stream,
                     emb, Wih, bih, bhh, Wx);
  hipLaunchKernelGGL(lstm_k2, dim3(64), dim3(512), 0, stream,
                     x, Whh, Wx, lastH);
  hipLaunchKernelGGL(head_k3, dim3(BATCH), dim3(OUTD), 0, stream,
                     lastH, Wout, bout, out);
}